// Round 7
// baseline (213.227 us; speedup 1.0000x reference)
//
#include <hip/hip_runtime.h>
#include <type_traits>

namespace {
constexpr int HH = 512;
constexpr int WW = 512;
constexpr int KS = 11;
constexpr int PADR = 5;
constexpr int TH = 32;                 // tile rows per block
constexpr int TW = 64;                 // tile cols per block
constexpr int HC = TW + 2 * PADR;      // 74 columns incl. horizontal halo
constexpr int LPA = 148;               // interleaved pair rows: 74 cols x 2
constexpr int LPC = 76;                // scalar sxy rows
constexpr int NTHREADS = 256;
constexpr int RROWS = 4;               // rows per wave-round
constexpr float SSIM_C1 = 1.0e-4f;     // (0.01*1.0)^2
constexpr float SSIM_C2 = 9.0e-4f;     // (0.03*1.0)^2
}

typedef float v2f __attribute__((ext_vector_type(2)));
typedef float v4f __attribute__((ext_vector_type(4)));
#define LOWP(v)  __builtin_shufflevector(v, v, 0, 1)
#define HIGHP(v) __builtin_shufflevector(v, v, 2, 3)

// R6 kernel (verified: 107us, VALUBusy 53%, occupancy 55% despite 6-block
// residency allowed) with ONE structural change: WAVE-INDEPENDENT execution.
// R6 post-mortem: the 4 __syncthreads()/block convoy all 4 waves on the
// slowest phase-1 tail (592/256=2.31 positions -> 3-position threads hold
// 256 threads) plus a full vmcnt/lgkmcnt drain each time -- that parking is
// why measured occupancy stays ~55%. Here each wave owns 8 output rows and
// a PRIVATE 5952B LDS region (4 rows x 5 stats per round, 2 rounds); no LDS
// crosses waves, so the barrier is replaced by a wave-internal
// s_waitcnt lgkmcnt(0) (DS ops of a wave execute in order; hazard is
// wave-local). Waves free-run: one wave's phase-2 VALU/LDS overlaps
// another's phase-1 global loads. Everything else byte-identical to R6.
__global__ __launch_bounds__(NTHREADS, 6) void ssim_fused(
    const float* __restrict__ x, const float* __restrict__ y,
    const float* __restrict__ kern, float* __restrict__ out)
{
    __shared__ __align__(16) float pA[4][RROWS * LPA];   // (sx,sy) per wave
    __shared__ __align__(16) float pB_[4][RROWS * LPA];  // (sxx,syy) per wave
    __shared__ __align__(16) float pC_[4][RROWS * LPC];  // sxy per wave
    // total 23808 B -> 6 blocks/CU = 142.8KB of 160KB LDS

    constexpr int tiles_w = WW / TW;         // 8
    constexpr int tiles_h = HH / TH;         // 16
    constexpr int tpp = tiles_w * tiles_h;   // 128 tiles per plane

    const int bid = blockIdx.x;
    const int plane = bid / tpp;
    const int trem = bid - plane * tpp;
    const int tr_idx = trem / tiles_w;
    const int tile_r = tr_idx * TH;
    const int tile_c = (trem - tr_idx * tiles_w) * TW;

    const float* __restrict__ xp = x + (size_t)plane * (HH * WW);
    const float* __restrict__ yp = y + (size_t)plane * (HH * WW);
    float* __restrict__ op = out + (size_t)plane * (HH * WW);

    // 1D gaussian weights (exact for outer products), broadcast pairs.
    // Kernel is symmetric: taps 6..10 mirror 4..0 -> 6 unique weights.
    v2f pw[6];
    {
        const float inv = rsqrtf(kern[5 * KS + 5]);
#pragma unroll
        for (int i = 0; i < 6; ++i) {
            const float w = kern[5 * KS + i] * inv;
            v2f tmp = {w, w};
            pw[i] = tmp;
        }
    }

    const int t = threadIdx.x;
    const int wv = t >> 6;             // wave id 0..3: owns rows 8*wv..8*wv+7
    const int lane = t & 63;
    const bool interior = (tile_r >= PADR) && (tile_r + TH + PADR <= HH) &&
                          (tile_c >= PADR) && (tile_c + TW + PADR <= WW);

    float* const wA = pA[wv];
    float* const wB = pB_[wv];
    float* const wC = pC_[wv];

    // phase-2 mapping within the wave's 4-row round window
    const int p2_r = lane >> 4;        // 0..3
    const int p2_m = lane & 15;        // col group; outputs 4*p2_m .. +3

    auto run_round = [&](int base_r, auto intr_tag) {
        constexpr bool INTR = decltype(intr_tag)::value;
        // ---- phase 1: vertical 11-tap blur into the wave's LDS region.
        // 2 row-pairs x 74 cols = 148 positions over 64 lanes.
        for (int i = lane; i < 2 * HC; i += 64) {
            const int r2 = (i >= HC) ? 1 : 0;
            const int c = i - r2 * HC;
            const int gr = base_r + 2 * r2;        // first output row of pair
            const int gc = tile_c + c - PADR;      // input col (maybe OOB)
            v2f uvA = {0.f, 0.f}, qqA = {0.f, 0.f};
            v2f uvB = {0.f, 0.f}, qqB = {0.f, 0.f};
            float xyA = 0.f, xyB = 0.f;
            const float* xq = xp + (gr - PADR) * WW + gc;
            const float* yq = yp + (gr - PADR) * WW + gc;
#pragma unroll
            for (int k = 0; k < KS + 1; ++k) {       // 12 input rows
                float xv, yv;
                if (INTR) {
                    xv = xq[k * WW];
                    yv = yq[k * WW];
                } else {
                    const int rr = gr - PADR + k;
                    const bool ok = (gc >= 0) & (gc < WW) & (rr >= 0) & (rr < HH);
                    xv = 0.f; yv = 0.f;
                    if (ok) {
                        xv = xp[rr * WW + gc];
                        yv = yp[rr * WW + gc];
                    }
                }
                v2f v2 = {xv, yv};
                const v2f q2 = v2 * v2;              // v_pk_mul_f32
                const float xy = xv * yv;
                if (k < KS) {                        // row A taps 0..10
                    const v2f w = pw[k < 6 ? k : 10 - k];
                    uvA += w * v2;                   // v_pk_fma_f32
                    qqA += w * q2;
                    xyA += w.x * xy;
                }
                if (k >= 1) {                        // row B taps 0..10
                    const v2f w = pw[(k - 1) < 6 ? (k - 1) : 11 - k];
                    uvB += w * v2;
                    qqB += w * q2;
                    xyB += w.x * xy;
                }
            }
            const int rA = 2 * r2, rB = 2 * r2 + 1;
            *(v2f*)&wA[rA * LPA + 2 * c] = uvA;  *(v2f*)&wA[rB * LPA + 2 * c] = uvB;
            *(v2f*)&wB[rA * LPA + 2 * c] = qqA;  *(v2f*)&wB[rB * LPA + 2 * c] = qqB;
            wC[rA * LPC + c] = xyA;              wC[rB * LPC + c] = xyB;
        }
        // wave-internal write->read ordering: DS ops of one wave execute in
        // order; drain lgkm so all lanes' staged rows are visible, and the
        // "memory" clobber pins compiler ordering of the LDS accesses.
        asm volatile("s_waitcnt lgkmcnt(0)" ::: "memory");

        // ---- phase 2: horizontal 11-tap blur (packed) + SSIM.
#define PCONV(R0, R1, R2, R3, a0, a1, a2, a3, a4, a5, a6)                       \
    R0 += pw[0]*LOWP(a0); R0 += pw[1]*HIGHP(a0); R0 += pw[2]*LOWP(a1);          \
    R0 += pw[3]*HIGHP(a1); R0 += pw[4]*LOWP(a2); R0 += pw[5]*HIGHP(a2);         \
    R0 += pw[4]*LOWP(a3); R0 += pw[3]*HIGHP(a3); R0 += pw[2]*LOWP(a4);          \
    R0 += pw[1]*HIGHP(a4); R0 += pw[0]*LOWP(a5);                                \
    R1 += pw[0]*HIGHP(a0); R1 += pw[1]*LOWP(a1); R1 += pw[2]*HIGHP(a1);         \
    R1 += pw[3]*LOWP(a2); R1 += pw[4]*HIGHP(a2); R1 += pw[5]*LOWP(a3);          \
    R1 += pw[4]*HIGHP(a3); R1 += pw[3]*LOWP(a4); R1 += pw[2]*HIGHP(a4);         \
    R1 += pw[1]*LOWP(a5); R1 += pw[0]*HIGHP(a5);                                \
    R2 += pw[0]*LOWP(a1); R2 += pw[1]*HIGHP(a1); R2 += pw[2]*LOWP(a2);          \
    R2 += pw[3]*HIGHP(a2); R2 += pw[4]*LOWP(a3); R2 += pw[5]*HIGHP(a3);         \
    R2 += pw[4]*LOWP(a4); R2 += pw[3]*HIGHP(a4); R2 += pw[2]*LOWP(a5);          \
    R2 += pw[1]*HIGHP(a5); R2 += pw[0]*LOWP(a6);                                \
    R3 += pw[0]*HIGHP(a1); R3 += pw[1]*LOWP(a2); R3 += pw[2]*HIGHP(a2);         \
    R3 += pw[3]*LOWP(a3); R3 += pw[4]*HIGHP(a3); R3 += pw[5]*LOWP(a4);          \
    R3 += pw[4]*HIGHP(a4); R3 += pw[3]*LOWP(a5); R3 += pw[2]*HIGHP(a5);         \
    R3 += pw[1]*LOWP(a6); R3 += pw[0]*HIGHP(a6);

#define SCONV(R, S0, S1, S2, S3, S4, S5, S6, S7, S8, S9, S10)                   \
    R += pw[0].x*S0; R += pw[1].x*S1; R += pw[2].x*S2; R += pw[3].x*S3;         \
    R += pw[4].x*S4; R += pw[5].x*S5; R += pw[4].x*S6; R += pw[3].x*S7;         \
    R += pw[2].x*S8; R += pw[1].x*S9; R += pw[0].x*S10;

        v2f rUV0 = {0.f, 0.f}, rUV1 = {0.f, 0.f}, rUV2 = {0.f, 0.f}, rUV3 = {0.f, 0.f};
        {
            const float* rowA = &wA[p2_r * LPA + 8 * p2_m];
            const v4f a0 = *(const v4f*)(rowA + 0);
            const v4f a1 = *(const v4f*)(rowA + 4);
            const v4f a2 = *(const v4f*)(rowA + 8);
            const v4f a3 = *(const v4f*)(rowA + 12);
            const v4f a4 = *(const v4f*)(rowA + 16);
            const v4f a5 = *(const v4f*)(rowA + 20);
            const v4f a6 = *(const v4f*)(rowA + 24);
            PCONV(rUV0, rUV1, rUV2, rUV3, a0, a1, a2, a3, a4, a5, a6)
        }
        v2f rQQ0 = {0.f, 0.f}, rQQ1 = {0.f, 0.f}, rQQ2 = {0.f, 0.f}, rQQ3 = {0.f, 0.f};
        {
            const float* rowB = &wB[p2_r * LPA + 8 * p2_m];
            const v4f a0 = *(const v4f*)(rowB + 0);
            const v4f a1 = *(const v4f*)(rowB + 4);
            const v4f a2 = *(const v4f*)(rowB + 8);
            const v4f a3 = *(const v4f*)(rowB + 12);
            const v4f a4 = *(const v4f*)(rowB + 16);
            const v4f a5 = *(const v4f*)(rowB + 20);
            const v4f a6 = *(const v4f*)(rowB + 24);
            PCONV(rQQ0, rQQ1, rQQ2, rQQ3, a0, a1, a2, a3, a4, a5, a6)
        }
        float rC0 = 0.f, rC1 = 0.f, rC2 = 0.f, rC3 = 0.f;
        {
            const float* rowC = &wC[p2_r * LPC + 4 * p2_m];
            const v4f c0 = *(const v4f*)(rowC + 0);
            const v4f c1 = *(const v4f*)(rowC + 4);
            const v4f c2 = *(const v4f*)(rowC + 8);
            const v4f c3 = *(const v4f*)(rowC + 12);
            const float e0 = c0.x, e1 = c0.y, e2 = c0.z, e3 = c0.w;
            const float e4 = c1.x, e5 = c1.y, e6 = c1.z, e7 = c1.w;
            const float e8 = c2.x, e9 = c2.y, e10 = c2.z, e11 = c2.w;
            const float e12 = c3.x, e13 = c3.y;
            SCONV(rC0, e0, e1, e2, e3, e4, e5, e6, e7, e8, e9, e10)
            SCONV(rC1, e1, e2, e3, e4, e5, e6, e7, e8, e9, e10, e11)
            SCONV(rC2, e2, e3, e4, e5, e6, e7, e8, e9, e10, e11, e12)
            SCONV(rC3, e3, e4, e5, e6, e7, e8, e9, e10, e11, e12, e13)
        }

        float4 o4;
#pragma unroll
        for (int j = 0; j < 4; ++j) {
            const v2f uvj = (j == 0) ? rUV0 : (j == 1) ? rUV1 : (j == 2) ? rUV2 : rUV3;
            const v2f qqj = (j == 0) ? rQQ0 : (j == 1) ? rQQ1 : (j == 2) ? rQQ2 : rQQ3;
            const float uxy = (j == 0) ? rC0 : (j == 1) ? rC1 : (j == 2) ? rC2 : rC3;
            const float ux = uvj.x, uy = uvj.y;
            const float uxx = qqj.x, uyy = qqj.y;
            const float vx  = uxx - ux * ux;
            const float vy  = uyy - uy * uy;
            const float vxy = uxy - ux * uy;
            const float a1s = 2.f * ux * uy + SSIM_C1;
            const float a2s = 2.f * vxy + SSIM_C2;
            const float b1s = ux * ux + uy * uy + SSIM_C1;
            const float b2s = vx + vy + SSIM_C2;
            (&o4.x)[j] = (a1s * a2s) * __builtin_amdgcn_rcpf(b1s * b2s);
        }
        *(float4*)(op + (size_t)(base_r + p2_r) * WW + (tile_c + 4 * p2_m)) = o4;
        // rounds reuse this wave's LDS region: the reads above were consumed
        // (results in registers) before the next round's writes can issue;
        // wave_barrier pins the compiler's round boundary.
        __builtin_amdgcn_wave_barrier();
#undef PCONV
#undef SCONV
    };

    const int wrow = tile_r + 8 * wv;       // this wave's first output row
    if (interior) {
        run_round(wrow,         std::true_type{});
        run_round(wrow + RROWS, std::true_type{});
    } else {
        run_round(wrow,         std::false_type{});
        run_round(wrow + RROWS, std::false_type{});
    }
}

extern "C" void kernel_launch(void* const* d_in, const int* in_sizes, int n_in,
                              void* d_out, int out_size, void* d_ws, size_t ws_size,
                              hipStream_t stream) {
    const float* x    = (const float*)d_in[0];
    const float* y    = (const float*)d_in[1];
    const float* kern = (const float*)d_in[2];
    float* out = (float*)d_out;

    const int nplanes = in_sizes[0] / (HH * WW);            // 48
    const int nblocks = nplanes * (HH / TH) * (WW / TW);    // 6144

    ssim_fused<<<dim3(nblocks), dim3(NTHREADS), 0, stream>>>(x, y, kern, out);
}